// Round 6
// baseline (20125.658 us; speedup 1.0000x reference)
//
#include <hip/hip_runtime.h>
#include <hip/hip_bf16.h>

#define T_STEPS 4096
#define I_DIM   512
#define H_DIM   2048
#define O_DIM   128
#define NBLK    256
#define THREADS 512   // 8 waves per block, 1 hidden unit per wave
#define WAVES_PER_BLK 8
#define SENTINEL 2.0f // |h| = |o*tanh(c)| <= 1.0 < 2.0, so 2.0f is unreachable

// Pre-fill hbuf with the sentinel so h-values are self-publishing.
__global__ void fill_sentinel(float4* __restrict__ p)
{
    p[(size_t)blockIdx.x * blockDim.x + threadIdx.x] =
        make_float4(SENTINEL, SENTINEL, SENTINEL, SENTINEL);
}

// Persistent LSTM: W_hh register-resident (64 MB chip-wide), one wave per
// hidden unit. NO grid barrier: readers spin on the data itself (write-once
// rows + sentinel; a 4B atomic store is indivisible, so a reader sees either
// SENTINEL or the final value). __launch_bounds__(512,2) caps VGPR at 256
// (wh=128 + wx=32 + temps fits) -> 8 waves/CU -> exactly 1 block/CU -> all
// 256 blocks co-resident -> data-spin cannot deadlock. Skew self-limits to 1
// step via the data dependence itself.
__global__ __launch_bounds__(THREADS, 2)
void lstm_persistent(const float* __restrict__ x,      // [T, I]
                     const float* __restrict__ W_ih,   // [4H, I]
                     const float* __restrict__ W_hh,   // [4H, H]
                     const float* __restrict__ b_ih,   // [4H]
                     const float* __restrict__ b_hh,   // [4H]
                     float* __restrict__ hbuf)         // [T, H] (ws, sentinel)
{
    const int tid  = threadIdx.x;
    const int wave = tid >> 6;
    const int lane = tid & 63;
    const int gate = lane >> 4;     // 0=i 1=f 2=g 3=o (PyTorch order)
    const int seg  = lane & 15;     // 16 segments x 128 elements over H
    const int rot  = seg & 7;       // x-read rotation (bank-conflict fix)
    const int j    = blockIdx.x * WAVES_PER_BLK + wave;   // hidden unit
    const int row  = gate * H_DIM + j;

    // ---- prologue: weights -> registers (one-time, HBM read-once) ----
    float4 wh[32];  // 128 fp32 of W_hh[row, seg*128 : seg*128+128]
    {
        const float4* whp = reinterpret_cast<const float4*>(
            W_hh + (size_t)row * H_DIM + (size_t)seg * 128);
        #pragma unroll
        for (int r = 0; r < 32; ++r) wh[r] = whp[r];
    }
    // wx[q] holds W_ih chunk ((q + rot) & 7) of this lane's 32-float slice,
    // matching the rotated LDS read below (distinct banks across segs).
    float4 wx[8];
    {
        const float* wxp = W_ih + (size_t)row * I_DIM + (size_t)seg * 32;
        #pragma unroll
        for (int q = 0; q < 8; ++q) {
            const int chunk = (q + rot) & 7;
            wx[q] = *reinterpret_cast<const float4*>(wxp + chunk * 4);
        }
    }
    const float bsum = b_ih[row] + b_hh[row];

    // LDS: h stage (16 segs x 132 floats, pad 4 -> worst 2-way = free;
    // 4 lanes sharing a seg read identical addresses -> broadcast, free)
    // and x double buffer (2 x 512 floats).
    __shared__ float hstage[16 * 132];
    __shared__ float xlds[2][I_DIM];

    xlds[0][tid] = x[tid];   // stage x[0] (coalesced, 1 float/thread)
    __syncthreads();

    float c = 0.0f;   // cell state, uniform across the wave

    for (int t = 0; t < T_STEPS; ++t) {
        const int cur = t & 1;

        // ---- issue h_{t-1} poll-loads FIRST (RTT overlaps x work below) ----
        float hv0 = 0.f, hv1 = 0.f, hv2 = 0.f, hv3 = 0.f;
        const float* hp = hbuf + (size_t)(t - 1) * H_DIM + tid;
        if (t > 0) {
            hv0 = __hip_atomic_load(hp + 0 * THREADS, __ATOMIC_RELAXED,
                                    __HIP_MEMORY_SCOPE_AGENT);
            hv1 = __hip_atomic_load(hp + 1 * THREADS, __ATOMIC_RELAXED,
                                    __HIP_MEMORY_SCOPE_AGENT);
            hv2 = __hip_atomic_load(hp + 2 * THREADS, __ATOMIC_RELAXED,
                                    __HIP_MEMORY_SCOPE_AGENT);
            hv3 = __hip_atomic_load(hp + 3 * THREADS, __ATOMIC_RELAXED,
                                    __HIP_MEMORY_SCOPE_AGENT);
        }

        // ---- prefetch x[t+1] into the other LDS buffer ----
        if (t + 1 < T_STEPS) {
            xlds[cur ^ 1][tid] = x[(size_t)(t + 1) * I_DIM + tid];
        }

        // ---- x-side contribution from LDS (independent of h_{t-1}) ----
        float acc;
        {
            const float4* xb = reinterpret_cast<const float4*>(&xlds[cur][0]);
            float4 a4 = make_float4(0.f, 0.f, 0.f, 0.f);
            #pragma unroll
            for (int q = 0; q < 8; ++q) {
                const int slot = (q + rot) & 7;   // runtime addr, static reg idx
                float4 xv = xb[seg * 8 + slot];
                a4.x = fmaf(wx[q].x, xv.x, a4.x);
                a4.y = fmaf(wx[q].y, xv.y, a4.y);
                a4.z = fmaf(wx[q].z, xv.z, a4.z);
                a4.w = fmaf(wx[q].w, xv.w, a4.w);
            }
            acc = (a4.x + a4.y) + (a4.z + a4.w);
        }

        if (t > 0) {
            // ---- data-spin: retry until all 4 values are published ----
            while (hv0 == SENTINEL || hv1 == SENTINEL ||
                   hv2 == SENTINEL || hv3 == SENTINEL) {
                __builtin_amdgcn_s_sleep(1);   // backoff: bounds L3 poll rate
                hv0 = __hip_atomic_load(hp + 0 * THREADS, __ATOMIC_RELAXED,
                                        __HIP_MEMORY_SCOPE_AGENT);
                hv1 = __hip_atomic_load(hp + 1 * THREADS, __ATOMIC_RELAXED,
                                        __HIP_MEMORY_SCOPE_AGENT);
                hv2 = __hip_atomic_load(hp + 2 * THREADS, __ATOMIC_RELAXED,
                                        __HIP_MEMORY_SCOPE_AGENT);
                hv3 = __hip_atomic_load(hp + 3 * THREADS, __ATOMIC_RELAXED,
                                        __HIP_MEMORY_SCOPE_AGENT);
            }
            // ---- stage h_{t-1} into LDS ----
            hstage[((tid + 0 * THREADS) >> 7) * 132 + ((tid + 0 * THREADS) & 127)] = hv0;
            hstage[((tid + 1 * THREADS) >> 7) * 132 + ((tid + 1 * THREADS) & 127)] = hv1;
            hstage[((tid + 2 * THREADS) >> 7) * 132 + ((tid + 2 * THREADS) & 127)] = hv2;
            hstage[((tid + 3 * THREADS) >> 7) * 132 + ((tid + 3 * THREADS) & 127)] = hv3;
        }
        __syncthreads();   // (A) hstage write -> read; also orders xlds reuse

        if (t > 0) {
            // ---- h-side dot: 128 FMAs from LDS ----
            const float4* hs4 =
                reinterpret_cast<const float4*>(&hstage[seg * 132]);
            float4 h4 = make_float4(0.f, 0.f, 0.f, 0.f);
            #pragma unroll
            for (int r = 0; r < 32; ++r) {
                float4 hv = hs4[r];
                h4.x = fmaf(wh[r].x, hv.x, h4.x);
                h4.y = fmaf(wh[r].y, hv.y, h4.y);
                h4.z = fmaf(wh[r].z, hv.z, h4.z);
                h4.w = fmaf(wh[r].w, hv.w, h4.w);
            }
            acc += (h4.x + h4.y) + (h4.z + h4.w);
        }

        // ---- butterfly reduce over the 16 seg lanes (per gate group) ----
        acc += __shfl_xor(acc, 1, 64);
        acc += __shfl_xor(acc, 2, 64);
        acc += __shfl_xor(acc, 4, 64);
        acc += __shfl_xor(acc, 8, 64);
        const float pre = acc + bsum;   // per-gate pre-activation

        // each gate group evaluates only ITS activation via HW exp
        // (v_exp_f32, ~2 ulp; injected into a contracting recurrence):
        //   sigmoid(p) = 1/(1+exp(-p));  tanh(p) = 1 - 2/(exp(2p)+1)
        const float q  = (gate == 2) ? (pre + pre) : (-pre);
        const float E  = __expf(q);
        const float rE = 1.0f / (1.0f + E);
        const float act = (gate == 2) ? (1.0f - 2.0f * rE) : rE;

        const float si = __shfl(act, 0, 64);
        const float sf = __shfl(act, 16, 64);
        const float gt = __shfl(act, 32, 64);
        const float so = __shfl(act, 48, 64);

        c = fmaf(sf, c, si * gt);
        const float Ec  = __expf(c + c);
        const float tc  = 1.0f - 2.0f / (1.0f + Ec);
        const float h_new = so * tc;   // |h_new| <= 1.0 < SENTINEL

        if (lane == 0) {
            __hip_atomic_store(hbuf + (size_t)t * H_DIM + j, h_new,
                               __ATOMIC_RELAXED, __HIP_MEMORY_SCOPE_AGENT);
        }
        __syncthreads();   // (B) hstage read(t) -> write(t+1); xlds reuse;
                           //     drains vmcnt so the publish store is issued
    }
}

// WdT[k][o] = W_d[o][k]  (1 MB, one-time, makes final GEMM loads coalesced)
__global__ void transpose_wd(const float* __restrict__ W_d,
                             float* __restrict__ WdT)
{
    const int idx = blockIdx.x * blockDim.x + threadIdx.x;
    const int o = idx & (O_DIM - 1);
    const int k = idx >> 7;
    if (k < H_DIM) WdT[(size_t)k * O_DIM + o] = W_d[(size_t)o * H_DIM + k];
}

// out[t][o] = b_d[o] + sum_k hs[t][k] * W_d[o][k]
#define TB 8
__global__ __launch_bounds__(256)
void dense_out(const float* __restrict__ hbuf, const float* __restrict__ WdT,
               const float* __restrict__ b_d, float* __restrict__ out)
{
    __shared__ float hs[TB][H_DIM];   // 64 KB
    const int t0 = blockIdx.x * TB;

    for (int i = threadIdx.x; i < TB * H_DIM / 4; i += 256) {
        reinterpret_cast<float4*>(&hs[0][0])[i] =
            reinterpret_cast<const float4*>(hbuf + (size_t)t0 * H_DIM)[i];
    }
    __syncthreads();

    const int o  = threadIdx.x & (O_DIM - 1);
    const int th = threadIdx.x >> 7;            // 0..1 -> 4 timesteps each
    float a0 = b_d[o], a1 = a0, a2 = a0, a3 = a0;
    for (int k = 0; k < H_DIM; ++k) {
        const float w = WdT[(size_t)k * O_DIM + o];
        a0 = fmaf(hs[th * 4 + 0][k], w, a0);
        a1 = fmaf(hs[th * 4 + 1][k], w, a1);
        a2 = fmaf(hs[th * 4 + 2][k], w, a2);
        a3 = fmaf(hs[th * 4 + 3][k], w, a3);
    }
    out[(size_t)(t0 + th * 4 + 0) * O_DIM + o] = a0;
    out[(size_t)(t0 + th * 4 + 1) * O_DIM + o] = a1;
    out[(size_t)(t0 + th * 4 + 2) * O_DIM + o] = a2;
    out[(size_t)(t0 + th * 4 + 3) * O_DIM + o] = a3;
}

extern "C" void kernel_launch(void* const* d_in, const int* in_sizes, int n_in,
                              void* d_out, int out_size, void* d_ws, size_t ws_size,
                              hipStream_t stream)
{
    (void)in_sizes; (void)n_in; (void)out_size; (void)ws_size;
    const float* x    = (const float*)d_in[0];
    const float* W_ih = (const float*)d_in[1];
    const float* W_hh = (const float*)d_in[2];
    const float* b_ih = (const float*)d_in[3];
    const float* b_hh = (const float*)d_in[4];
    const float* W_d  = (const float*)d_in[5];
    const float* b_d  = (const float*)d_in[6];
    float* out = (float*)d_out;

    char* ws = (char*)d_ws;
    float* hbuf = (float*)ws;                                   // 32 MB
    float* WdT  = (float*)(ws + (size_t)T_STEPS * H_DIM * 4);   // 1 MB

    // sentinel-fill hbuf every launch (ws is re-poisoned before every call)
    fill_sentinel<<<(T_STEPS * H_DIM / 4) / 256, 256, 0, stream>>>(
        (float4*)hbuf);
    transpose_wd<<<(H_DIM * O_DIM) / 256, 256, 0, stream>>>(W_d, WdT);
    lstm_persistent<<<NBLK, THREADS, 0, stream>>>(x, W_ih, W_hh, b_ih, b_hh,
                                                  hbuf);
    dense_out<<<T_STEPS / TB, 256, 0, stream>>>(hbuf, WdT, b_d, out);
}

// Round 7
// 14436.780 us; speedup vs baseline: 1.3941x; 1.3941x over previous
//
#include <hip/hip_runtime.h>
#include <hip/hip_bf16.h>

#define T_STEPS 4096
#define I_DIM   512
#define H_DIM   2048
#define O_DIM   128
#define NBLK    256
#define THREADS 512   // 8 waves per block, 1 hidden unit per wave
#define WAVES_PER_BLK 8
#define SENTINEL 2.0f // |h| = |o*tanh(c)| <= 1.0 < 2.0, so 2.0f is unreachable

// Opaque pin: value becomes asm-defined -> compiler cannot rematerialize it
// from memory; must keep it live in VGPRs across the loop.
#define PIN2(v) asm volatile("" : "+v"((v).x), "+v"((v).y))

__global__ void fill_sentinel(float4* __restrict__ p)
{
    p[(size_t)blockIdx.x * blockDim.x + threadIdx.x] =
        make_float4(SENTINEL, SENTINEL, SENTINEL, SENTINEL);
}

// Persistent LSTM: W_hh pinned register-resident (64 MB chip-wide), one wave
// per hidden unit, lane owns a 32-float h-slice for ALL 4 gates.
// Data-is-sync: readers spin on sentinel-filled hbuf (write-once rows).
// 256 blocks x 512 thr, launch_bounds(512,2) -> <=256 VGPR -> 1 block/CU,
// all 256 blocks co-resident -> spin cannot deadlock.
__global__ __launch_bounds__(THREADS, 2)
void lstm_persistent(const float* __restrict__ x,      // [T, I]
                     const float* __restrict__ W_ih,   // [4H, I]
                     const float* __restrict__ W_hh,   // [4H, H]
                     const float* __restrict__ b_ih,   // [4H]
                     const float* __restrict__ b_hh,   // [4H]
                     float* __restrict__ hbuf)         // [T, H] (ws, sentinel)
{
    const int tid  = threadIdx.x;
    const int wave = tid >> 6;
    const int lane = tid & 63;
    const int j    = blockIdx.x * WAVES_PER_BLK + wave;   // hidden unit

    // ---- prologue: weight slices -> registers (one-time) ----
    // wh2[g][c] = W_hh[g*H+j][lane*32 + 2c .. +1]   (128 floats = 128 VGPR)
    // wx2[g][c] = W_ih[g*H+j][lane*8  + 2c .. +1]   (32 floats)
    float2 wh2[4][16];
    float2 wx2[4][4];
    float  bs[4];
    #pragma unroll
    for (int g = 0; g < 4; ++g) {
        const int row = g * H_DIM + j;
        const float2* wp = reinterpret_cast<const float2*>(
            W_hh + (size_t)row * H_DIM + lane * 32);
        #pragma unroll
        for (int c = 0; c < 16; ++c) wh2[g][c] = wp[c];
        const float2* xp = reinterpret_cast<const float2*>(
            W_ih + (size_t)row * I_DIM + lane * 8);
        #pragma unroll
        for (int c = 0; c < 4; ++c) wx2[g][c] = xp[c];
        bs[g] = b_ih[row] + b_hh[row];
    }
    // pin all weight registers (defeats rematerialization-from-memory)
    #pragma unroll
    for (int g = 0; g < 4; ++g) {
        #pragma unroll
        for (int c = 0; c < 16; ++c) PIN2(wh2[g][c]);
        #pragma unroll
        for (int c = 0; c < 4; ++c)  PIN2(wx2[g][c]);
    }

    // LDS, conflict-free layouts:
    //  hstage: slice l at dword 34*l (pad 32->34): b64 read offset 34l+2c
    //          -> banks (2l+2c)%32 distinct within every 16-lane phase.
    //  xlds:   slice l at dword 10*l (pad 8->10): b64 read offset 10l+2c
    //          -> banks (10l+2c)%32 distinct within every 16-lane phase.
    __shared__ float hstage[64 * 34];           // 8704 B
    __shared__ float xlds[2][64 * 10];          // 5120 B

    xlds[0][10 * (tid >> 3) + (tid & 7)] = x[tid];   // stage x[0]
    __syncthreads();

    float c = 0.0f;   // cell state, uniform across the wave

    for (int t = 0; t < T_STEPS; ++t) {
        const int cur = t & 1;

        // ---- issue h_{t-1} poll-loads FIRST (RTT overlaps x-dot) ----
        float hv0 = 0.f, hv1 = 0.f, hv2 = 0.f, hv3 = 0.f;
        const float* hp = hbuf + (size_t)(t - 1) * H_DIM + tid;
        if (t > 0) {
            hv0 = __hip_atomic_load(hp + 0 * THREADS, __ATOMIC_RELAXED,
                                    __HIP_MEMORY_SCOPE_AGENT);
            hv1 = __hip_atomic_load(hp + 1 * THREADS, __ATOMIC_RELAXED,
                                    __HIP_MEMORY_SCOPE_AGENT);
            hv2 = __hip_atomic_load(hp + 2 * THREADS, __ATOMIC_RELAXED,
                                    __HIP_MEMORY_SCOPE_AGENT);
            hv3 = __hip_atomic_load(hp + 3 * THREADS, __ATOMIC_RELAXED,
                                    __HIP_MEMORY_SCOPE_AGENT);
        }

        // ---- prefetch x[t+1] ----
        if (t + 1 < T_STEPS) {
            xlds[cur ^ 1][10 * (tid >> 3) + (tid & 7)] =
                x[(size_t)(t + 1) * I_DIM + tid];
        }

        // ---- x-dot: 8 floats/lane, conflict-free b64 reads ----
        float a0 = 0.f, a1 = 0.f, a2 = 0.f, a3 = 0.f;
        {
            const float* xb = &xlds[cur][0];
            #pragma unroll
            for (int cc = 0; cc < 4; ++cc) {
                const float2 xv =
                    *reinterpret_cast<const float2*>(xb + 10 * lane + 2 * cc);
                a0 = fmaf(wx2[0][cc].x, xv.x, fmaf(wx2[0][cc].y, xv.y, a0));
                a1 = fmaf(wx2[1][cc].x, xv.x, fmaf(wx2[1][cc].y, xv.y, a1));
                a2 = fmaf(wx2[2][cc].x, xv.x, fmaf(wx2[2][cc].y, xv.y, a2));
                a3 = fmaf(wx2[3][cc].x, xv.x, fmaf(wx2[3][cc].y, xv.y, a3));
            }
        }

        if (t > 0) {
            // ---- data-spin until all 4 h values are published ----
            while (hv0 == SENTINEL || hv1 == SENTINEL ||
                   hv2 == SENTINEL || hv3 == SENTINEL) {
                __builtin_amdgcn_s_sleep(1);
                hv0 = __hip_atomic_load(hp + 0 * THREADS, __ATOMIC_RELAXED,
                                        __HIP_MEMORY_SCOPE_AGENT);
                hv1 = __hip_atomic_load(hp + 1 * THREADS, __ATOMIC_RELAXED,
                                        __HIP_MEMORY_SCOPE_AGENT);
                hv2 = __hip_atomic_load(hp + 2 * THREADS, __ATOMIC_RELAXED,
                                        __HIP_MEMORY_SCOPE_AGENT);
                hv3 = __hip_atomic_load(hp + 3 * THREADS, __ATOMIC_RELAXED,
                                        __HIP_MEMORY_SCOPE_AGENT);
            }
            // ---- stage h_{t-1}: value g -> hstage[34*(g>>5) + (g&31)] ----
            hstage[34 * ((tid + 0 * THREADS) >> 5) + ((tid + 0 * THREADS) & 31)] = hv0;
            hstage[34 * ((tid + 1 * THREADS) >> 5) + ((tid + 1 * THREADS) & 31)] = hv1;
            hstage[34 * ((tid + 2 * THREADS) >> 5) + ((tid + 2 * THREADS) & 31)] = hv2;
            hstage[34 * ((tid + 3 * THREADS) >> 5) + ((tid + 3 * THREADS) & 31)] = hv3;
        }
        __syncthreads();   // (A) hstage publish; also fences xlds buffers

        if (t > 0) {
            // ---- h-dot: 32 floats/lane x 4 gates, conflict-free b64 ----
            const float* hb = hstage + 34 * lane;
            #pragma unroll
            for (int cc = 0; cc < 16; ++cc) {
                const float2 hv =
                    *reinterpret_cast<const float2*>(hb + 2 * cc);
                a0 = fmaf(wh2[0][cc].x, hv.x, fmaf(wh2[0][cc].y, hv.y, a0));
                a1 = fmaf(wh2[1][cc].x, hv.x, fmaf(wh2[1][cc].y, hv.y, a1));
                a2 = fmaf(wh2[2][cc].x, hv.x, fmaf(wh2[2][cc].y, hv.y, a2));
                a3 = fmaf(wh2[3][cc].x, hv.x, fmaf(wh2[3][cc].y, hv.y, a3));
            }
        }

        // ---- full-wave butterfly: all lanes end with all 4 gate sums ----
        #pragma unroll
        for (int m = 1; m < 64; m <<= 1) {
            a0 += __shfl_xor(a0, m, 64);
            a1 += __shfl_xor(a1, m, 64);
            a2 += __shfl_xor(a2, m, 64);
            a3 += __shfl_xor(a3, m, 64);
        }

        // ---- gates (uniform across wave), HW exp ----
        const float si = 1.0f / (1.0f + __expf(-(a0 + bs[0])));
        const float sf = 1.0f / (1.0f + __expf(-(a1 + bs[1])));
        const float gt = 1.0f - 2.0f / (1.0f + __expf(2.0f * (a2 + bs[2])));
        const float so = 1.0f / (1.0f + __expf(-(a3 + bs[3])));

        c = fmaf(sf, c, si * gt);
        const float tc = 1.0f - 2.0f / (1.0f + __expf(2.0f * c));
        const float h_new = so * tc;   // |h_new| <= 1.0 < SENTINEL

        if (lane == 0) {
            __hip_atomic_store(hbuf + (size_t)t * H_DIM + j, h_new,
                               __ATOMIC_RELAXED, __HIP_MEMORY_SCOPE_AGENT);
        }
        __syncthreads();   // (B) hstage read(t) -> write(t+1); xlds reuse
    }
}

// WdT[k][o] = W_d[o][k]  (1 MB, one-time, makes final GEMM loads coalesced)
__global__ void transpose_wd(const float* __restrict__ W_d,
                             float* __restrict__ WdT)
{
    const int idx = blockIdx.x * blockDim.x + threadIdx.x;
    const int o = idx & (O_DIM - 1);
    const int k = idx >> 7;
    if (k < H_DIM) WdT[(size_t)k * O_DIM + o] = W_d[(size_t)o * H_DIM + k];
}

// out[t][o] = b_d[o] + sum_k hs[t][k] * W_d[o][k]
#define TB 8
__global__ __launch_bounds__(256)
void dense_out(const float* __restrict__ hbuf, const float* __restrict__ WdT,
               const float* __restrict__ b_d, float* __restrict__ out)
{
    __shared__ float hs[TB][H_DIM];   // 64 KB
    const int t0 = blockIdx.x * TB;

    for (int i = threadIdx.x; i < TB * H_DIM / 4; i += 256) {
        reinterpret_cast<float4*>(&hs[0][0])[i] =
            reinterpret_cast<const float4*>(hbuf + (size_t)t0 * H_DIM)[i];
    }
    __syncthreads();

    const int o  = threadIdx.x & (O_DIM - 1);
    const int th = threadIdx.x >> 7;            // 0..1 -> 4 timesteps each
    float a0 = b_d[o], a1 = a0, a2 = a0, a3 = a0;
    for (int k = 0; k < H_DIM; ++k) {
        const float w = WdT[(size_t)k * O_DIM + o];
        a0 = fmaf(hs[th * 4 + 0][k], w, a0);
        a1 = fmaf(hs[th * 4 + 1][k], w, a1);
        a2 = fmaf(hs[th * 4 + 2][k], w, a2);
        a3 = fmaf(hs[th * 4 + 3][k], w, a3);
    }
    out[(size_t)(t0 + th * 4 + 0) * O_DIM + o] = a0;
    out[(size_t)(t0 + th * 4 + 1) * O_DIM + o] = a1;
    out[(size_t)(t0 + th * 4 + 2) * O_DIM + o] = a2;
    out[(size_t)(t0 + th * 4 + 3) * O_DIM + o] = a3;
}

extern "C" void kernel_launch(void* const* d_in, const int* in_sizes, int n_in,
                              void* d_out, int out_size, void* d_ws, size_t ws_size,
                              hipStream_t stream)
{
    (void)in_sizes; (void)n_in; (void)out_size; (void)ws_size;
    const float* x    = (const float*)d_in[0];
    const float* W_ih = (const float*)d_in[1];
    const float* W_hh = (const float*)d_in[2];
    const float* b_ih = (const float*)d_in[3];
    const float* b_hh = (const float*)d_in[4];
    const float* W_d  = (const float*)d_in[5];
    const float* b_d  = (const float*)d_in[6];
    float* out = (float*)d_out;

    char* ws = (char*)d_ws;
    float* hbuf = (float*)ws;                                   // 32 MB
    float* WdT  = (float*)(ws + (size_t)T_STEPS * H_DIM * 4);   // 1 MB

    fill_sentinel<<<(T_STEPS * H_DIM / 4) / 256, 256, 0, stream>>>(
        (float4*)hbuf);
    transpose_wd<<<(H_DIM * O_DIM) / 256, 256, 0, stream>>>(W_d, WdT);
    lstm_persistent<<<NBLK, THREADS, 0, stream>>>(x, W_ih, W_hh, b_ih, b_hh,
                                                  hbuf);
    dense_out<<<T_STEPS / TB, 256, 0, stream>>>(hbuf, WdT, b_d, out);
}

// Round 8
// 14347.948 us; speedup vs baseline: 1.4027x; 1.0062x over previous
//
#include <hip/hip_runtime.h>
#include <hip/hip_bf16.h>

#define T_STEPS 4096
#define I_DIM   512
#define H_DIM   2048
#define O_DIM   128
#define NBLK    256
#define THREADS 512   // 8 waves per block, 1 hidden unit per wave
#define WAVES_PER_BLK 8
#define SENTINEL 2.0f // |h| = |o*tanh(c)| <= 1.0 < 2.0, so 2.0f is unreachable

// Opaque pin: value becomes asm-defined -> compiler cannot rematerialize it
// from memory; must keep it live (and with waves_per_eu(2,2) it has no
// occupancy motive to spill it to scratch either).
#define PIN2(v) asm volatile("" : "+v"((v).x), "+v"((v).y))

__global__ void fill_sentinel(float4* __restrict__ p)
{
    p[(size_t)blockIdx.x * blockDim.x + threadIdx.x] =
        make_float4(SENTINEL, SENTINEL, SENTINEL, SENTINEL);
}

// Persistent LSTM: W_hh register-resident (64 MB chip-wide), one wave per
// hidden unit, lane owns a contiguous 32-float h-slice for ALL 4 gates.
// Data-is-sync: readers spin on sentinel-filled hbuf (write-once rows).
// amdgpu_waves_per_eu(2,2): pins the allocator's occupancy target to
// exactly 2 waves/EU -> full 256-VGPR budget -> no scratch spills of the
// 164 pinned weight registers. 256 blocks x 512 thr -> 1 block/CU, all
// co-resident -> data-spin cannot deadlock.
__global__
__attribute__((amdgpu_flat_work_group_size(THREADS, THREADS),
               amdgpu_waves_per_eu(2, 2)))
void lstm_persistent(const float* __restrict__ x,      // [T, I]
                     const float* __restrict__ W_ih,   // [4H, I]
                     const float* __restrict__ W_hh,   // [4H, H]
                     const float* __restrict__ b_ih,   // [4H]
                     const float* __restrict__ b_hh,   // [4H]
                     float* __restrict__ hbuf)         // [T, H] (ws, sentinel)
{
    const int tid  = threadIdx.x;
    const int wave = tid >> 6;
    const int lane = tid & 63;
    const int j    = blockIdx.x * WAVES_PER_BLK + wave;   // hidden unit

    // ---- prologue: weight slices -> registers (one-time) ----
    // wh2[g][c] = W_hh[g*H+j][lane*32 + 2c .. +1]   (128 floats = 128 VGPR)
    // wx2[g][c] = W_ih[g*H+j][lane*8  + 2c .. +1]   (32 floats)
    float2 wh2[4][16];
    float2 wx2[4][4];
    float  bs[4];
    #pragma unroll
    for (int g = 0; g < 4; ++g) {
        const int row = g * H_DIM + j;
        const float2* wp = reinterpret_cast<const float2*>(
            W_hh + (size_t)row * H_DIM + lane * 32);
        #pragma unroll
        for (int c = 0; c < 16; ++c) wh2[g][c] = wp[c];
        const float2* xp = reinterpret_cast<const float2*>(
            W_ih + (size_t)row * I_DIM + lane * 8);
        #pragma unroll
        for (int c = 0; c < 4; ++c) wx2[g][c] = xp[c];
        bs[g] = b_ih[row] + b_hh[row];
    }
    // pin all weight registers (defeats rematerialization-from-memory)
    #pragma unroll
    for (int g = 0; g < 4; ++g) {
        #pragma unroll
        for (int c = 0; c < 16; ++c) PIN2(wh2[g][c]);
        #pragma unroll
        for (int c = 0; c < 4; ++c)  PIN2(wx2[g][c]);
    }

    // LDS, conflict-free layouts:
    //  hstage: slice l at dword 34*l (pad 32->34): b64 read offset 34l+2c
    //          -> banks (2l+2c)%32 distinct within every 16-lane phase.
    //  xlds:   slice l at dword 10*l (pad 8->10): b64 read offset 10l+2c
    //          -> banks distinct within every 16-lane phase.
    __shared__ float hstage[64 * 34];           // 8704 B
    __shared__ float xlds[2][64 * 10];          // 5120 B

    xlds[0][10 * (tid >> 3) + (tid & 7)] = x[tid];   // stage x[0]
    __syncthreads();

    float c = 0.0f;   // cell state, uniform across the wave

    for (int t = 0; t < T_STEPS; ++t) {
        const int cur = t & 1;

        // ---- issue h_{t-1} poll-loads FIRST (RTT overlaps x-dot) ----
        float hv0 = 0.f, hv1 = 0.f, hv2 = 0.f, hv3 = 0.f;
        const float* hp = hbuf + (size_t)(t - 1) * H_DIM + tid;
        if (t > 0) {
            hv0 = __hip_atomic_load(hp + 0 * THREADS, __ATOMIC_RELAXED,
                                    __HIP_MEMORY_SCOPE_AGENT);
            hv1 = __hip_atomic_load(hp + 1 * THREADS, __ATOMIC_RELAXED,
                                    __HIP_MEMORY_SCOPE_AGENT);
            hv2 = __hip_atomic_load(hp + 2 * THREADS, __ATOMIC_RELAXED,
                                    __HIP_MEMORY_SCOPE_AGENT);
            hv3 = __hip_atomic_load(hp + 3 * THREADS, __ATOMIC_RELAXED,
                                    __HIP_MEMORY_SCOPE_AGENT);
        }

        // ---- prefetch x[t+1] ----
        if (t + 1 < T_STEPS) {
            xlds[cur ^ 1][10 * (tid >> 3) + (tid & 7)] =
                x[(size_t)(t + 1) * I_DIM + tid];
        }

        // ---- x-dot: 8 floats/lane, conflict-free b64 reads ----
        float a0 = 0.f, a1 = 0.f, a2 = 0.f, a3 = 0.f;
        {
            const float* xb = &xlds[cur][0];
            #pragma unroll
            for (int cc = 0; cc < 4; ++cc) {
                const float2 xv =
                    *reinterpret_cast<const float2*>(xb + 10 * lane + 2 * cc);
                a0 = fmaf(wx2[0][cc].x, xv.x, fmaf(wx2[0][cc].y, xv.y, a0));
                a1 = fmaf(wx2[1][cc].x, xv.x, fmaf(wx2[1][cc].y, xv.y, a1));
                a2 = fmaf(wx2[2][cc].x, xv.x, fmaf(wx2[2][cc].y, xv.y, a2));
                a3 = fmaf(wx2[3][cc].x, xv.x, fmaf(wx2[3][cc].y, xv.y, a3));
            }
        }

        if (t > 0) {
            // ---- data-spin until all 4 h values are published ----
            while (hv0 == SENTINEL || hv1 == SENTINEL ||
                   hv2 == SENTINEL || hv3 == SENTINEL) {
                __builtin_amdgcn_s_sleep(1);
                hv0 = __hip_atomic_load(hp + 0 * THREADS, __ATOMIC_RELAXED,
                                        __HIP_MEMORY_SCOPE_AGENT);
                hv1 = __hip_atomic_load(hp + 1 * THREADS, __ATOMIC_RELAXED,
                                        __HIP_MEMORY_SCOPE_AGENT);
                hv2 = __hip_atomic_load(hp + 2 * THREADS, __ATOMIC_RELAXED,
                                        __HIP_MEMORY_SCOPE_AGENT);
                hv3 = __hip_atomic_load(hp + 3 * THREADS, __ATOMIC_RELAXED,
                                        __HIP_MEMORY_SCOPE_AGENT);
            }
            // ---- stage h_{t-1}: value g -> hstage[34*(g>>5) + (g&31)] ----
            hstage[34 * ((tid + 0 * THREADS) >> 5) + ((tid + 0 * THREADS) & 31)] = hv0;
            hstage[34 * ((tid + 1 * THREADS) >> 5) + ((tid + 1 * THREADS) & 31)] = hv1;
            hstage[34 * ((tid + 2 * THREADS) >> 5) + ((tid + 2 * THREADS) & 31)] = hv2;
            hstage[34 * ((tid + 3 * THREADS) >> 5) + ((tid + 3 * THREADS) & 31)] = hv3;
        }
        __syncthreads();   // (A) hstage publish; also fences xlds buffers

        if (t > 0) {
            // ---- h-dot: 32 floats/lane x 4 gates, conflict-free b64 ----
            const float* hb = hstage + 34 * lane;
            #pragma unroll
            for (int cc = 0; cc < 16; ++cc) {
                const float2 hv =
                    *reinterpret_cast<const float2*>(hb + 2 * cc);
                a0 = fmaf(wh2[0][cc].x, hv.x, fmaf(wh2[0][cc].y, hv.y, a0));
                a1 = fmaf(wh2[1][cc].x, hv.x, fmaf(wh2[1][cc].y, hv.y, a1));
                a2 = fmaf(wh2[2][cc].x, hv.x, fmaf(wh2[2][cc].y, hv.y, a2));
                a3 = fmaf(wh2[3][cc].x, hv.x, fmaf(wh2[3][cc].y, hv.y, a3));
            }
        }

        // ---- full-wave butterfly: all lanes end with all 4 gate sums ----
        #pragma unroll
        for (int m = 1; m < 64; m <<= 1) {
            a0 += __shfl_xor(a0, m, 64);
            a1 += __shfl_xor(a1, m, 64);
            a2 += __shfl_xor(a2, m, 64);
            a3 += __shfl_xor(a3, m, 64);
        }

        // ---- gates (uniform across wave), HW exp ----
        const float si = 1.0f / (1.0f + __expf(-(a0 + bs[0])));
        const float sf = 1.0f / (1.0f + __expf(-(a1 + bs[1])));
        const float gt = 1.0f - 2.0f / (1.0f + __expf(2.0f * (a2 + bs[2])));
        const float so = 1.0f / (1.0f + __expf(-(a3 + bs[3])));

        c = fmaf(sf, c, si * gt);
        const float tc = 1.0f - 2.0f / (1.0f + __expf(2.0f * c));
        const float h_new = so * tc;   // |h_new| <= 1.0 < SENTINEL

        if (lane == 0) {
            __hip_atomic_store(hbuf + (size_t)t * H_DIM + j, h_new,
                               __ATOMIC_RELAXED, __HIP_MEMORY_SCOPE_AGENT);
        }
        __syncthreads();   // (B) hstage read(t) -> write(t+1); xlds reuse
    }
}

// WdT[k][o] = W_d[o][k]  (1 MB, one-time, makes final GEMM loads coalesced)
__global__ void transpose_wd(const float* __restrict__ W_d,
                             float* __restrict__ WdT)
{
    const int idx = blockIdx.x * blockDim.x + threadIdx.x;
    const int o = idx & (O_DIM - 1);
    const int k = idx >> 7;
    if (k < H_DIM) WdT[(size_t)k * O_DIM + o] = W_d[(size_t)o * H_DIM + k];
}

// out[t][o] = b_d[o] + sum_k hs[t][k] * W_d[o][k]
#define TB 8
__global__ __launch_bounds__(256)
void dense_out(const float* __restrict__ hbuf, const float* __restrict__ WdT,
               const float* __restrict__ b_d, float* __restrict__ out)
{
    __shared__ float hs[TB][H_DIM];   // 64 KB
    const int t0 = blockIdx.x * TB;

    for (int i = threadIdx.x; i < TB * H_DIM / 4; i += 256) {
        reinterpret_cast<float4*>(&hs[0][0])[i] =
            reinterpret_cast<const float4*>(hbuf + (size_t)t0 * H_DIM)[i];
    }
    __syncthreads();

    const int o  = threadIdx.x & (O_DIM - 1);
    const int th = threadIdx.x >> 7;            // 0..1 -> 4 timesteps each
    float a0 = b_d[o], a1 = a0, a2 = a0, a3 = a0;
    for (int k = 0; k < H_DIM; ++k) {
        const float w = WdT[(size_t)k * O_DIM + o];
        a0 = fmaf(hs[th * 4 + 0][k], w, a0);
        a1 = fmaf(hs[th * 4 + 1][k], w, a1);
        a2 = fmaf(hs[th * 4 + 2][k], w, a2);
        a3 = fmaf(hs[th * 4 + 3][k], w, a3);
    }
    out[(size_t)(t0 + th * 4 + 0) * O_DIM + o] = a0;
    out[(size_t)(t0 + th * 4 + 1) * O_DIM + o] = a1;
    out[(size_t)(t0 + th * 4 + 2) * O_DIM + o] = a2;
    out[(size_t)(t0 + th * 4 + 3) * O_DIM + o] = a3;
}

extern "C" void kernel_launch(void* const* d_in, const int* in_sizes, int n_in,
                              void* d_out, int out_size, void* d_ws, size_t ws_size,
                              hipStream_t stream)
{
    (void)in_sizes; (void)n_in; (void)out_size; (void)ws_size;
    const float* x    = (const float*)d_in[0];
    const float* W_ih = (const float*)d_in[1];
    const float* W_hh = (const float*)d_in[2];
    const float* b_ih = (const float*)d_in[3];
    const float* b_hh = (const float*)d_in[4];
    const float* W_d  = (const float*)d_in[5];
    const float* b_d  = (const float*)d_in[6];
    float* out = (float*)d_out;

    char* ws = (char*)d_ws;
    float* hbuf = (float*)ws;                                   // 32 MB
    float* WdT  = (float*)(ws + (size_t)T_STEPS * H_DIM * 4);   // 1 MB

    fill_sentinel<<<(T_STEPS * H_DIM / 4) / 256, 256, 0, stream>>>(
        (float4*)hbuf);
    transpose_wd<<<(H_DIM * O_DIM) / 256, 256, 0, stream>>>(W_d, WdT);
    lstm_persistent<<<NBLK, THREADS, 0, stream>>>(x, W_ih, W_hh, b_ih, b_hh,
                                                  hbuf);
    dense_out<<<T_STEPS / TB, 256, 0, stream>>>(hbuf, WdT, b_d, out);
}